// Round 2
// baseline (1180.101 us; speedup 1.0000x reference)
//
#include <hip/hip_runtime.h>

#define N_NODES 100000
#define N_EDGES 1600000

typedef __attribute__((ext_vector_type(8))) short bf16x8;
typedef __attribute__((ext_vector_type(4))) float f32x4;
typedef __attribute__((ext_vector_type(4))) unsigned short u16x4;

__device__ __forceinline__ float b2f(unsigned short u) {
    union { unsigned int i; float f; } v; v.i = ((unsigned int)u) << 16; return v.f;
}
__device__ __forceinline__ unsigned short f2b(float f) {
    union { float ff; unsigned int i; } v; v.ff = f;
    unsigned int x = v.i;
    x += 0x7fffu + ((x >> 16) & 1u);   // round-to-nearest-even
    return (unsigned short)(x >> 16);
}

// ---------------- f32 -> bf16 cast (n divisible by 4) ----------------
__global__ __launch_bounds__(256) void k_cast4(const float* __restrict__ in,
                                               unsigned short* __restrict__ out, int n4) {
    int i = blockIdx.x * 256 + threadIdx.x;
    if (i < n4) {
        f32x4 v = *(const f32x4*)&in[(size_t)i * 4];
        u16x4 o;
        o[0] = f2b(v[0]); o[1] = f2b(v[1]); o[2] = f2b(v[2]); o[3] = f2b(v[3]);
        *(u16x4*)&out[(size_t)i * 4] = o;
    }
}

// ---------------- graph build ----------------
__global__ void k_init_deg(int* deg) {
    int i = blockIdx.x * 256 + threadIdx.x;
    if (i < N_NODES) deg[i] = 1;   // self-loop
}

__global__ void k_hist(const int* __restrict__ dst, int* __restrict__ deg) {
    int e = blockIdx.x * 256 + threadIdx.x;
    if (e < N_EDGES) atomicAdd(&deg[dst[e]], 1);
}

// single block, 1024 threads: exclusive scan of deg -> row_ptr, cursor; dinv = rsqrt(deg)
__global__ void k_scan(const int* __restrict__ deg, int* __restrict__ row_ptr,
                       int* __restrict__ cursor, float* __restrict__ dinv) {
    __shared__ int sm[1024];
    const int t = threadIdx.x;
    const int CH = (N_NODES + 1023) / 1024;   // 98
    int beg = t * CH, end = min(beg + CH, N_NODES);
    int s = 0;
    for (int i = beg; i < end; ++i) s += deg[i];
    sm[t] = s; __syncthreads();
    for (int off = 1; off < 1024; off <<= 1) {
        int v = (t >= off) ? sm[t - off] : 0;
        __syncthreads();
        sm[t] += v;
        __syncthreads();
    }
    int run = (t == 0) ? 0 : sm[t - 1];
    for (int i = beg; i < end; ++i) {
        row_ptr[i] = run; cursor[i] = run;
        int d = deg[i]; run += d;
        dinv[i] = rsqrtf((float)d);
    }
}

__global__ void k_scatter(const int* __restrict__ src, const int* __restrict__ dst,
                          int* __restrict__ cursor, int* __restrict__ ssrc) {
    int e = blockIdx.x * 256 + threadIdx.x;
    if (e < N_EDGES) {
        int p = atomicAdd(&cursor[dst[e]], 1);
        ssrc[p] = src[e];
    }
}

// ---------------- GEMM: out[n,128] = relu?( concat(A0..A_{NC-1}) @ W + bias? ) ----------------
// A chunks and W are bf16 (pre-cast); accumulate f32; out bf16.
// W is [(NC*128) x 128] row-major bf16. Block = 256 thr (4 waves), 64 rows/block, 128 cols.
template<int NC, bool RELU, bool BIAS>
__global__ __launch_bounds__(256) void k_gemm(
    const unsigned short* __restrict__ A0, const unsigned short* __restrict__ A1,
    const unsigned short* __restrict__ A2, const unsigned short* __restrict__ W,
    const float* __restrict__ bias, unsigned short* __restrict__ out)
{
    __shared__ unsigned short Wt[128 * 136];   // [col][k], pad 8 -> 272B stride (16B-aligned)
    const int tid  = threadIdx.x;
    const int wave = tid >> 6, lane = tid & 63;
    const int l15 = lane & 15, lg = lane >> 4;
    const int row_base = blockIdx.x * 64 + wave * 16;

    f32x4 acc[8];
#pragma unroll
    for (int i = 0; i < 8; ++i) acc[i] = (f32x4)(0.0f);

    int arow = row_base + l15; if (arow >= N_NODES) arow = N_NODES - 1;

    for (int c = 0; c < NC; ++c) {
        const unsigned short* Ac = (c == 0) ? A0 : ((c == 1) ? A1 : A2);
        __syncthreads();
        // stage W chunk c transposed into LDS: Wt[col][k]
#pragma unroll
        for (int it = 0; it < 32; ++it) {
            int idx = tid + it * 256;        // 0..8191 = 128 cols x 64 row-pairs
            int col = idx & 127;
            int rp  = idx >> 7;
            unsigned short w0 = W[(size_t)(c * 128 + 2 * rp) * 128 + col];
            unsigned short w1 = W[(size_t)(c * 128 + 2 * rp + 1) * 128 + col];
            unsigned int pk = (unsigned int)w0 | ((unsigned int)w1 << 16);
            *(unsigned int*)&Wt[col * 136 + 2 * rp] = pk;
        }
        __syncthreads();
#pragma unroll
        for (int ks = 0; ks < 4; ++ks) {
            bf16x8 a = *(const bf16x8*)&Ac[(size_t)arow * 128 + ks * 32 + lg * 8];
#pragma unroll
            for (int cf = 0; cf < 8; ++cf) {
                bf16x8 b = *(const bf16x8*)&Wt[(cf * 16 + l15) * 136 + ks * 32 + lg * 8];
                acc[cf] = __builtin_amdgcn_mfma_f32_16x16x32_bf16(a, b, acc[cf], 0, 0, 0);
            }
        }
    }
    // epilogue: C/D layout col = lane&15, row = (lane>>4)*4 + j
#pragma unroll
    for (int cf = 0; cf < 8; ++cf) {
        int col = cf * 16 + l15;
        float bv = BIAS ? bias[col] : 0.0f;
#pragma unroll
        for (int j = 0; j < 4; ++j) {
            int row = row_base + lg * 4 + j;
            if (row < N_NODES) {
                float v = acc[cf][j] + bv;
                if (RELU) v = fmaxf(v, 0.0f);
                out[(size_t)row * 128 + col] = f2b(v);
            }
        }
    }
}

// ---------------- aggregation: out = relu(dinv_i * sum(dinv_s * t_s) + dinv_i^2 * t_i + b) ----------------
// t is bf16 [n,128]; one wave per node, 2 feats/lane; FINAL writes f32, else bf16.
template<bool FINAL>
__global__ __launch_bounds__(256) void k_agg(
    const unsigned short* __restrict__ t, const int* __restrict__ ssrc,
    const int* __restrict__ row_ptr, const int* __restrict__ deg,
    const float* __restrict__ dinv, const float* __restrict__ bias,
    void* __restrict__ out_v)
{
    const int wave = threadIdx.x >> 6;
    const int lane = threadIdx.x & 63;
    const int node = blockIdx.x * 4 + wave;
    if (node >= N_NODES) return;

    const int beg = row_ptr[node];
    const int cnt = deg[node] - 1;       // edges only; self handled below
    float a0 = 0.0f, a1 = 0.0f;
    for (int k = 0; k < cnt; ++k) {
        int s = ssrc[beg + k];
        float w = dinv[s];
        unsigned int pk = *(const unsigned int*)&t[(size_t)s * 128 + lane * 2];
        a0 += w * b2f((unsigned short)(pk & 0xffffu));
        a1 += w * b2f((unsigned short)(pk >> 16));
    }
    float di = dinv[node];
    unsigned int ps = *(const unsigned int*)&t[(size_t)node * 128 + lane * 2];
    float s0 = b2f((unsigned short)(ps & 0xffffu));
    float s1 = b2f((unsigned short)(ps >> 16));
    float o0 = fmaxf(di * a0 + di * di * s0 + bias[lane * 2], 0.0f);
    float o1 = fmaxf(di * a1 + di * di * s1 + bias[lane * 2 + 1], 0.0f);
    if (FINAL) {
        float* out = (float*)out_v;
        out[(size_t)node * 128 + lane * 2]     = o0;
        out[(size_t)node * 128 + lane * 2 + 1] = o1;
    } else {
        unsigned short* out = (unsigned short*)out_v;
        unsigned int po = (unsigned int)f2b(o0) | ((unsigned int)f2b(o1) << 16);
        *(unsigned int*)&out[(size_t)node * 128 + lane * 2] = po;
    }
}

// ---------------- launch ----------------
extern "C" void kernel_launch(void* const* d_in, const int* in_sizes, int n_in,
                              void* d_out, int out_size, void* d_ws, size_t ws_size,
                              hipStream_t stream)
{
    const float* x  = (const float*)d_in[0];
    const int*   ei = (const int*)d_in[1];
    const float* pW = (const float*)d_in[2];
    const float* pb = (const float*)d_in[3];
    const float* W1 = (const float*)d_in[4];
    const float* b1 = (const float*)d_in[5];
    const float* W2 = (const float*)d_in[6];
    const float* b2 = (const float*)d_in[7];
    const float* W3 = (const float*)d_in[8];
    const float* b3 = (const float*)d_in[9];
    const int* src = ei;
    const int* dst = ei + N_EDGES;

    char* ws = (char*)d_ws;
    size_t off = 0;
    auto alloc = [&](size_t bytes) -> char* {
        char* p = ws + off; off += (bytes + 255) & ~(size_t)255; return p;
    };
    const size_t NB = (size_t)N_NODES * 128;
    unsigned short* xb = (unsigned short*)alloc(NB * 2);   // x cast to bf16
    unsigned short* xp = (unsigned short*)alloc(NB * 2);
    unsigned short* h1 = (unsigned short*)alloc(NB * 2);
    unsigned short* h2 = (unsigned short*)alloc(NB * 2);
    unsigned short* tb = (unsigned short*)alloc(NB * 2);
    unsigned short* Wb = (unsigned short*)alloc((size_t)114688 * 2);  // pW|W1|W2|W3 bf16
    int*   deg  = (int*)alloc((size_t)N_NODES * 4);
    int*   rp   = (int*)alloc((size_t)N_NODES * 4);
    int*   cur  = (int*)alloc((size_t)N_NODES * 4);
    float* dinv = (float*)alloc((size_t)N_NODES * 4);
    int*   ssrc = (int*)alloc((size_t)(N_EDGES + N_NODES) * 4);

    unsigned short* pWb = Wb;
    unsigned short* W1b = Wb + 16384;
    unsigned short* W2b = Wb + 32768;
    unsigned short* W3b = Wb + 65536;

    // casts
    k_cast4<<<(int)(NB / 4 + 255) / 256, 256, 0, stream>>>(x, xb, (int)(NB / 4));
    k_cast4<<<16, 256, 0, stream>>>(pW, pWb, 4096);
    k_cast4<<<16, 256, 0, stream>>>(W1, W1b, 4096);
    k_cast4<<<32, 256, 0, stream>>>(W2, W2b, 8192);
    k_cast4<<<48, 256, 0, stream>>>(W3, W3b, 12288);

    // graph build
    k_init_deg<<<(N_NODES + 255) / 256, 256, 0, stream>>>(deg);
    k_hist<<<(N_EDGES + 255) / 256, 256, 0, stream>>>(dst, deg);
    k_scan<<<1, 1024, 0, stream>>>(deg, rp, cur, dinv);
    k_scatter<<<(N_EDGES + 255) / 256, 256, 0, stream>>>(src, dst, cur, ssrc);

    const int gblocks = (N_NODES + 63) / 64;
    const int ablocks = (N_NODES + 3) / 4;

    // x_p = relu(x @ proj_W + proj_b)
    k_gemm<1, true, true><<<gblocks, 256, 0, stream>>>(xb, nullptr, nullptr, pWb, pb, xp);
    // h1 = relu(agg(x @ W1) + b1)
    k_gemm<1, false, false><<<gblocks, 256, 0, stream>>>(xb, nullptr, nullptr, W1b, nullptr, tb);
    k_agg<false><<<ablocks, 256, 0, stream>>>(tb, ssrc, rp, deg, dinv, b1, h1);
    // h2 = relu(agg([x_p,h1] @ W2) + b2)
    k_gemm<2, false, false><<<gblocks, 256, 0, stream>>>(xp, h1, nullptr, W2b, nullptr, tb);
    k_agg<false><<<ablocks, 256, 0, stream>>>(tb, ssrc, rp, deg, dinv, b2, h2);
    // h3 = relu(agg([x_p,h1,h2] @ W3) + b3)  -> d_out (f32)
    k_gemm<3, false, false><<<gblocks, 256, 0, stream>>>(xp, h1, h2, W3b, nullptr, tb);
    k_agg<true><<<ablocks, 256, 0, stream>>>(tb, ssrc, rp, deg, dinv, b3, d_out);
}

// Round 3
// 906.747 us; speedup vs baseline: 1.3015x; 1.3015x over previous
//
#include <hip/hip_runtime.h>

#define N_NODES 100000
#define N_EDGES 1600000

typedef __attribute__((ext_vector_type(8))) short bf16x8;
typedef __attribute__((ext_vector_type(4))) float f32x4;
typedef __attribute__((ext_vector_type(4))) unsigned short u16x4;

__device__ __forceinline__ float b2f(unsigned short u) {
    union { unsigned int i; float f; } v; v.i = ((unsigned int)u) << 16; return v.f;
}
__device__ __forceinline__ unsigned short f2b(float f) {
    union { float ff; unsigned int i; } v; v.ff = f;
    unsigned int x = v.i;
    x += 0x7fffu + ((x >> 16) & 1u);   // round-to-nearest-even
    return (unsigned short)(x >> 16);
}

// ---------------- f32 -> bf16 casts ----------------
__global__ __launch_bounds__(256) void k_cast4(const float* __restrict__ in,
                                               unsigned short* __restrict__ out, int n4) {
    int i = blockIdx.x * 256 + threadIdx.x;
    if (i < n4) {
        f32x4 v = *(const f32x4*)&in[(size_t)i * 4];
        u16x4 o;
        o[0] = f2b(v[0]); o[1] = f2b(v[1]); o[2] = f2b(v[2]); o[3] = f2b(v[3]);
        *(u16x4*)&out[(size_t)i * 4] = o;
    }
}

// all 4 weight matrices in one launch; out = contiguous pW|W1|W2|W3 (bf16)
__global__ __launch_bounds__(256) void k_castW(
    const float* __restrict__ pW, const float* __restrict__ W1,
    const float* __restrict__ W2, const float* __restrict__ W3,
    unsigned short* __restrict__ out)
{
    int i = blockIdx.x * 256 + threadIdx.x;   // k4 index, 28672 total
    if (i >= 28672) return;
    const float* src; int so;
    if (i < 4096)       { src = pW; so = i * 4; }
    else if (i < 8192)  { src = W1; so = (i - 4096) * 4; }
    else if (i < 16384) { src = W2; so = (i - 8192) * 4; }
    else                { src = W3; so = (i - 16384) * 4; }
    f32x4 v = *(const f32x4*)&src[so];
    u16x4 o;
    o[0] = f2b(v[0]); o[1] = f2b(v[1]); o[2] = f2b(v[2]); o[3] = f2b(v[3]);
    *(u16x4*)&out[(size_t)i * 4] = o;
}

// ---------------- graph build ----------------
__global__ void k_init_deg(int* deg) {
    int i = blockIdx.x * 256 + threadIdx.x;
    if (i < N_NODES) deg[i] = 1;   // self-loop
}

__global__ void k_hist(const int* __restrict__ dst, int* __restrict__ deg) {
    int e = blockIdx.x * 256 + threadIdx.x;
    if (e < N_EDGES) atomicAdd(&deg[dst[e]], 1);
}

// -------- multi-block exclusive scan of deg (CHUNK=2048/block, 49 blocks) --------
#define SCAN_CHUNK 2048
#define SCAN_BLOCKS ((N_NODES + SCAN_CHUNK - 1) / SCAN_CHUNK)   // 49

__global__ __launch_bounds__(256) void k_deg_part(const int* __restrict__ deg,
                                                  int* __restrict__ psum) {
    int b = blockIdx.x, t = threadIdx.x;
    int base = b * SCAN_CHUNK + t * 8;
    int s = 0;
#pragma unroll
    for (int i = 0; i < 8; ++i) { int idx = base + i; if (idx < N_NODES) s += deg[idx]; }
    for (int o = 1; o < 64; o <<= 1) s += __shfl_xor(s, o, 64);
    __shared__ int ws[4];
    if ((t & 63) == 0) ws[t >> 6] = s;
    __syncthreads();
    if (t == 0) psum[b] = ws[0] + ws[1] + ws[2] + ws[3];
}

__global__ void k_scan_off(const int* __restrict__ psum, int* __restrict__ poff) {
    int t = threadIdx.x;          // 64 threads, SCAN_BLOCKS <= 64
    int v = (t < SCAN_BLOCKS) ? psum[t] : 0;
    int sc = v;
    for (int o = 1; o < 64; o <<= 1) { int u = __shfl_up(sc, o, 64); if (t >= o) sc += u; }
    if (t < SCAN_BLOCKS) poff[t] = sc - v;
}

__global__ __launch_bounds__(256) void k_scan_final(
    const int* __restrict__ deg, const int* __restrict__ poff,
    int* __restrict__ row_ptr, int* __restrict__ cursor, float* __restrict__ dinv)
{
    int b = blockIdx.x, t = threadIdx.x;
    int base = b * SCAN_CHUNK + t * 8;
    int v[8]; int s = 0;
#pragma unroll
    for (int i = 0; i < 8; ++i) { int idx = base + i; v[i] = (idx < N_NODES) ? deg[idx] : 0; s += v[i]; }
    int lane = t & 63, wv = t >> 6;
    int sc = s;
    for (int o = 1; o < 64; o <<= 1) { int u = __shfl_up(sc, o, 64); if (lane >= o) sc += u; }
    __shared__ int wsum[4];
    if (lane == 63) wsum[wv] = sc;
    __syncthreads();
    int woff = 0;
    for (int i = 0; i < wv; ++i) woff += wsum[i];
    int excl = poff[b] + woff + sc - s;
#pragma unroll
    for (int i = 0; i < 8; ++i) {
        int idx = base + i;
        if (idx < N_NODES) {
            row_ptr[idx] = excl; cursor[idx] = excl;
            dinv[idx] = rsqrtf((float)v[i]);
            excl += v[i];
        }
    }
}

__global__ void k_scatter(const int* __restrict__ src, const int* __restrict__ dst,
                          int* __restrict__ cursor, int* __restrict__ ssrc) {
    int e = blockIdx.x * 256 + threadIdx.x;
    if (e < N_EDGES) {
        int p = atomicAdd(&cursor[dst[e]], 1);
        ssrc[p] = src[e];
    }
}

// ---------------- GEMM: out[n,128] = relu?( concat(A0..A_{NC-1}) @ W + bias? ) ----------------
template<int NC, bool RELU, bool BIAS>
__global__ __launch_bounds__(256) void k_gemm(
    const unsigned short* __restrict__ A0, const unsigned short* __restrict__ A1,
    const unsigned short* __restrict__ A2, const unsigned short* __restrict__ W,
    const float* __restrict__ bias, unsigned short* __restrict__ out)
{
    __shared__ unsigned short Wt[128 * 136];   // [col][k], pad 8
    const int tid  = threadIdx.x;
    const int wave = tid >> 6, lane = tid & 63;
    const int l15 = lane & 15, lg = lane >> 4;
    const int row_base = blockIdx.x * 64 + wave * 16;

    f32x4 acc[8];
#pragma unroll
    for (int i = 0; i < 8; ++i) acc[i] = (f32x4)(0.0f);

    int arow = row_base + l15; if (arow >= N_NODES) arow = N_NODES - 1;

    for (int c = 0; c < NC; ++c) {
        const unsigned short* Ac = (c == 0) ? A0 : ((c == 1) ? A1 : A2);
        __syncthreads();
#pragma unroll
        for (int it = 0; it < 32; ++it) {
            int idx = tid + it * 256;
            int col = idx & 127;
            int rp  = idx >> 7;
            unsigned short w0 = W[(size_t)(c * 128 + 2 * rp) * 128 + col];
            unsigned short w1 = W[(size_t)(c * 128 + 2 * rp + 1) * 128 + col];
            unsigned int pk = (unsigned int)w0 | ((unsigned int)w1 << 16);
            *(unsigned int*)&Wt[col * 136 + 2 * rp] = pk;
        }
        __syncthreads();
#pragma unroll
        for (int ks = 0; ks < 4; ++ks) {
            bf16x8 a = *(const bf16x8*)&Ac[(size_t)arow * 128 + ks * 32 + lg * 8];
#pragma unroll
            for (int cf = 0; cf < 8; ++cf) {
                bf16x8 b = *(const bf16x8*)&Wt[(cf * 16 + l15) * 136 + ks * 32 + lg * 8];
                acc[cf] = __builtin_amdgcn_mfma_f32_16x16x32_bf16(a, b, acc[cf], 0, 0, 0);
            }
        }
    }
#pragma unroll
    for (int cf = 0; cf < 8; ++cf) {
        int col = cf * 16 + l15;
        float bv = BIAS ? bias[col] : 0.0f;
#pragma unroll
        for (int j = 0; j < 4; ++j) {
            int row = row_base + lg * 4 + j;
            if (row < N_NODES) {
                float v = acc[cf][j] + bv;
                if (RELU) v = fmaxf(v, 0.0f);
                out[(size_t)row * 128 + col] = f2b(v);
            }
        }
    }
}

// ---------------- aggregation ----------------
template<bool FINAL>
__global__ __launch_bounds__(256) void k_agg(
    const unsigned short* __restrict__ t, const int* __restrict__ ssrc,
    const int* __restrict__ row_ptr, const int* __restrict__ deg,
    const float* __restrict__ dinv, const float* __restrict__ bias,
    void* __restrict__ out_v)
{
    const int wave = threadIdx.x >> 6;
    const int lane = threadIdx.x & 63;
    const int node = blockIdx.x * 4 + wave;
    if (node >= N_NODES) return;

    const int beg = row_ptr[node];
    const int cnt = deg[node] - 1;
    float a0 = 0.0f, a1 = 0.0f;
    for (int k = 0; k < cnt; ++k) {
        int s = ssrc[beg + k];
        float w = dinv[s];
        unsigned int pk = *(const unsigned int*)&t[(size_t)s * 128 + lane * 2];
        a0 += w * b2f((unsigned short)(pk & 0xffffu));
        a1 += w * b2f((unsigned short)(pk >> 16));
    }
    float di = dinv[node];
    unsigned int ps = *(const unsigned int*)&t[(size_t)node * 128 + lane * 2];
    float s0 = b2f((unsigned short)(ps & 0xffffu));
    float s1 = b2f((unsigned short)(ps >> 16));
    float o0 = fmaxf(di * a0 + di * di * s0 + bias[lane * 2], 0.0f);
    float o1 = fmaxf(di * a1 + di * di * s1 + bias[lane * 2 + 1], 0.0f);
    if (FINAL) {
        float* out = (float*)out_v;
        out[(size_t)node * 128 + lane * 2]     = o0;
        out[(size_t)node * 128 + lane * 2 + 1] = o1;
    } else {
        unsigned short* out = (unsigned short*)out_v;
        unsigned int po = (unsigned int)f2b(o0) | ((unsigned int)f2b(o1) << 16);
        *(unsigned int*)&out[(size_t)node * 128 + lane * 2] = po;
    }
}

// ---------------- launch ----------------
extern "C" void kernel_launch(void* const* d_in, const int* in_sizes, int n_in,
                              void* d_out, int out_size, void* d_ws, size_t ws_size,
                              hipStream_t stream)
{
    const float* x  = (const float*)d_in[0];
    const int*   ei = (const int*)d_in[1];
    const float* pW = (const float*)d_in[2];
    const float* pb = (const float*)d_in[3];
    const float* W1 = (const float*)d_in[4];
    const float* b1 = (const float*)d_in[5];
    const float* W2 = (const float*)d_in[6];
    const float* b2 = (const float*)d_in[7];
    const float* W3 = (const float*)d_in[8];
    const float* b3 = (const float*)d_in[9];
    const int* src = ei;
    const int* dst = ei + N_EDGES;

    char* ws = (char*)d_ws;
    size_t off = 0;
    auto alloc = [&](size_t bytes) -> char* {
        char* p = ws + off; off += (bytes + 255) & ~(size_t)255; return p;
    };
    const size_t NB = (size_t)N_NODES * 128;
    unsigned short* xb = (unsigned short*)alloc(NB * 2);
    unsigned short* xp = (unsigned short*)alloc(NB * 2);
    unsigned short* h1 = (unsigned short*)alloc(NB * 2);
    unsigned short* h2 = (unsigned short*)alloc(NB * 2);
    unsigned short* tb = (unsigned short*)alloc(NB * 2);
    unsigned short* Wb = (unsigned short*)alloc((size_t)114688 * 2);
    int*   deg  = (int*)alloc((size_t)N_NODES * 4);
    int*   rp   = (int*)alloc((size_t)N_NODES * 4);
    int*   cur  = (int*)alloc((size_t)N_NODES * 4);
    float* dinv = (float*)alloc((size_t)N_NODES * 4);
    int*   psum = (int*)alloc((size_t)SCAN_BLOCKS * 4);
    int*   poff = (int*)alloc((size_t)SCAN_BLOCKS * 4);
    int*   ssrc = (int*)alloc((size_t)(N_EDGES + N_NODES) * 4);

    unsigned short* pWb = Wb;
    unsigned short* W1b = Wb + 16384;
    unsigned short* W2b = Wb + 32768;
    unsigned short* W3b = Wb + 65536;

    // casts
    k_cast4<<<(int)(NB / 4 + 255) / 256, 256, 0, stream>>>(x, xb, (int)(NB / 4));
    k_castW<<<(28672 + 255) / 256, 256, 0, stream>>>(pW, W1, W2, W3, Wb);

    // graph build
    k_init_deg<<<(N_NODES + 255) / 256, 256, 0, stream>>>(deg);
    k_hist<<<(N_EDGES + 255) / 256, 256, 0, stream>>>(dst, deg);
    k_deg_part<<<SCAN_BLOCKS, 256, 0, stream>>>(deg, psum);
    k_scan_off<<<1, 64, 0, stream>>>(psum, poff);
    k_scan_final<<<SCAN_BLOCKS, 256, 0, stream>>>(deg, poff, rp, cur, dinv);
    k_scatter<<<(N_EDGES + 255) / 256, 256, 0, stream>>>(src, dst, cur, ssrc);

    const int gblocks = (N_NODES + 63) / 64;
    const int ablocks = (N_NODES + 3) / 4;

    k_gemm<1, true, true><<<gblocks, 256, 0, stream>>>(xb, nullptr, nullptr, pWb, pb, xp);
    k_gemm<1, false, false><<<gblocks, 256, 0, stream>>>(xb, nullptr, nullptr, W1b, nullptr, tb);
    k_agg<false><<<ablocks, 256, 0, stream>>>(tb, ssrc, rp, deg, dinv, b1, h1);
    k_gemm<2, false, false><<<gblocks, 256, 0, stream>>>(xp, h1, nullptr, W2b, nullptr, tb);
    k_agg<false><<<ablocks, 256, 0, stream>>>(tb, ssrc, rp, deg, dinv, b2, h2);
    k_gemm<3, false, false><<<gblocks, 256, 0, stream>>>(xp, h1, h2, W3b, nullptr, tb);
    k_agg<true><<<ablocks, 256, 0, stream>>>(tb, ssrc, rp, deg, dinv, b3, d_out);
}

// Round 5
// 685.042 us; speedup vs baseline: 1.7227x; 1.3236x over previous
//
#include <hip/hip_runtime.h>

#define N_NODES 100000
#define N_EDGES 1600000

typedef __attribute__((ext_vector_type(8))) short bf16x8;
typedef __attribute__((ext_vector_type(4))) float f32x4;
typedef __attribute__((ext_vector_type(2))) float f32x2;
typedef __attribute__((ext_vector_type(4))) unsigned short u16x4;

__device__ __forceinline__ float b2f(unsigned short u) {
    union { unsigned int i; float f; } v; v.i = ((unsigned int)u) << 16; return v.f;
}
__device__ __forceinline__ unsigned short f2b(float f) {
    union { float ff; unsigned int i; } v; v.ff = f;
    unsigned int x = v.i;
    x += 0x7fffu + ((x >> 16) & 1u);   // round-to-nearest-even
    return (unsigned short)(x >> 16);
}
__device__ __forceinline__ float rdlanef(float v, int l) {
    return __uint_as_float(__builtin_amdgcn_readlane(__float_as_uint(v), l));
}

// ---------------- f32 -> bf16 cast of x ----------------
__global__ __launch_bounds__(256) void k_cast4(const float* __restrict__ in,
                                               unsigned short* __restrict__ out, int n4) {
    int i = blockIdx.x * 256 + threadIdx.x;
    if (i < n4) {
        f32x4 v = *(const f32x4*)&in[(size_t)i * 4];
        u16x4 o;
        o[0] = f2b(v[0]); o[1] = f2b(v[1]); o[2] = f2b(v[2]); o[3] = f2b(v[3]);
        *(u16x4*)&out[(size_t)i * 4] = o;
    }
}

// cast + TRANSPOSE all 4 weight matrices -> Wt[col][k] bf16, contiguous pW|W1|W2|W3
__global__ __launch_bounds__(256) void k_castWT(
    const float* __restrict__ pW, const float* __restrict__ W1,
    const float* __restrict__ W2, const float* __restrict__ W3,
    unsigned short* __restrict__ out)
{
    int i = blockIdx.x * 256 + threadIdx.x;   // flat output index, 114688 total
    if (i >= 114688) return;
    const float* src; int K, base;
    if (i < 16384)      { src = pW; K = 128; base = 0; }
    else if (i < 32768) { src = W1; K = 128; base = 16384; }
    else if (i < 65536) { src = W2; K = 256; base = 32768; }
    else                { src = W3; K = 384; base = 65536; }
    int loc = i - base;
    int col = loc / K, k = loc - col * K;
    out[i] = f2b(src[(size_t)k * 128 + col]);   // write coalesced, read strided (tiny, once)
}

// ---------------- graph build ----------------
__global__ void k_init_deg(int* deg) {
    int i = blockIdx.x * 256 + threadIdx.x;
    if (i < N_NODES) deg[i] = 1;   // self-loop
}

__global__ void k_hist(const int* __restrict__ dst, int* __restrict__ deg) {
    int e = blockIdx.x * 256 + threadIdx.x;
    if (e < N_EDGES) atomicAdd(&deg[dst[e]], 1);
}

#define SCAN_CHUNK 2048
#define SCAN_BLOCKS ((N_NODES + SCAN_CHUNK - 1) / SCAN_CHUNK)   // 49

__global__ __launch_bounds__(256) void k_deg_part(const int* __restrict__ deg,
                                                  int* __restrict__ psum) {
    int b = blockIdx.x, t = threadIdx.x;
    int base = b * SCAN_CHUNK + t * 8;
    int s = 0;
#pragma unroll
    for (int i = 0; i < 8; ++i) { int idx = base + i; if (idx < N_NODES) s += deg[idx]; }
    for (int o = 1; o < 64; o <<= 1) s += __shfl_xor(s, o, 64);
    __shared__ int ws[4];
    if ((t & 63) == 0) ws[t >> 6] = s;
    __syncthreads();
    if (t == 0) psum[b] = ws[0] + ws[1] + ws[2] + ws[3];
}

__global__ void k_scan_off(const int* __restrict__ psum, int* __restrict__ poff) {
    int t = threadIdx.x;          // 64 threads
    int v = (t < SCAN_BLOCKS) ? psum[t] : 0;
    int sc = v;
    for (int o = 1; o < 64; o <<= 1) { int u = __shfl_up(sc, o, 64); if (t >= o) sc += u; }
    if (t < SCAN_BLOCKS) poff[t] = sc - v;
}

__global__ __launch_bounds__(256) void k_scan_final(
    const int* __restrict__ deg, const int* __restrict__ poff,
    int* __restrict__ row_ptr, int* __restrict__ cursor, float* __restrict__ dinv)
{
    int b = blockIdx.x, t = threadIdx.x;
    int base = b * SCAN_CHUNK + t * 8;
    int v[8]; int s = 0;
#pragma unroll
    for (int i = 0; i < 8; ++i) { int idx = base + i; v[i] = (idx < N_NODES) ? deg[idx] : 0; s += v[i]; }
    int lane = t & 63, wv = t >> 6;
    int sc = s;
    for (int o = 1; o < 64; o <<= 1) { int u = __shfl_up(sc, o, 64); if (lane >= o) sc += u; }
    __shared__ int wsum[4];
    if (lane == 63) wsum[wv] = sc;
    __syncthreads();
    int woff = 0;
    for (int i = 0; i < wv; ++i) woff += wsum[i];
    int excl = poff[b] + woff + sc - s;
#pragma unroll
    for (int i = 0; i < 8; ++i) {
        int idx = base + i;
        if (idx < N_NODES) {
            row_ptr[idx] = excl; cursor[idx] = excl;
            dinv[idx] = rsqrtf((float)v[i]);
            excl += v[i];
        }
    }
}

__global__ void k_scatter(const int* __restrict__ src, const int* __restrict__ dst,
                          int* __restrict__ cursor, int* __restrict__ ssrc) {
    int e = blockIdx.x * 256 + threadIdx.x;
    if (e < N_EDGES) {
        int p = atomicAdd(&cursor[dst[e]], 1);
        ssrc[p] = src[e];
    }
}

// ---------------- GEMM: out[n,128] = relu?( concat(A0..A_{NC-1}) @ W + bias? ) ----------------
// B-fragments read directly from global W^T (L2-resident). No LDS, no barriers.
// 256 thr = 4 waves; 32 rows/wave -> 128 rows/block.
template<int NC, bool RELU, bool BIAS>
__global__ __launch_bounds__(256) void k_gemm(
    const unsigned short* __restrict__ A0, const unsigned short* __restrict__ A1,
    const unsigned short* __restrict__ A2, const unsigned short* __restrict__ WtG,
    const float* __restrict__ bias, unsigned short* __restrict__ out)
{
    const int tid  = threadIdx.x;
    const int wave = tid >> 6, lane = tid & 63;
    const int l15 = lane & 15, lg = lane >> 4;
    const int K = NC * 128;
    const int rbase = blockIdx.x * 128 + wave * 32;

    f32x4 acc[2][8];
#pragma unroll
    for (int i = 0; i < 2; ++i)
#pragma unroll
        for (int j = 0; j < 8; ++j) acc[i][j] = (f32x4)(0.0f);

    int ar0 = rbase + l15;      if (ar0 >= N_NODES) ar0 = N_NODES - 1;
    int ar1 = rbase + 16 + l15; if (ar1 >= N_NODES) ar1 = N_NODES - 1;

    for (int c = 0; c < NC; ++c) {
        const unsigned short* Ac = (c == 0) ? A0 : ((c == 1) ? A1 : A2);
#pragma unroll
        for (int ks = 0; ks < 4; ++ks) {
            const int ko = ks * 32 + lg * 8;
            bf16x8 a0 = *(const bf16x8*)&Ac[(size_t)ar0 * 128 + ko];
            bf16x8 a1 = *(const bf16x8*)&Ac[(size_t)ar1 * 128 + ko];
#pragma unroll
            for (int cf = 0; cf < 8; ++cf) {
                bf16x8 b = *(const bf16x8*)&WtG[(size_t)(cf * 16 + l15) * K + c * 128 + ko];
                acc[0][cf] = __builtin_amdgcn_mfma_f32_16x16x32_bf16(a0, b, acc[0][cf], 0, 0, 0);
                acc[1][cf] = __builtin_amdgcn_mfma_f32_16x16x32_bf16(a1, b, acc[1][cf], 0, 0, 0);
            }
        }
    }
#pragma unroll
    for (int ai = 0; ai < 2; ++ai) {
#pragma unroll
        for (int cf = 0; cf < 8; ++cf) {
            int col = cf * 16 + l15;
            float bv = BIAS ? bias[col] : 0.0f;
#pragma unroll
            for (int j = 0; j < 4; ++j) {
                int row = rbase + ai * 16 + lg * 4 + j;
                if (row < N_NODES) {
                    float v = acc[ai][cf][j] + bv;
                    if (RELU) v = fmaxf(v, 0.0f);
                    out[(size_t)row * 128 + col] = f2b(v);
                }
            }
        }
    }
}

// ---------------- aggregation: out = relu(dinv_i * sum(dinv_s * t_s) + dinv_i^2 * t_i + b) ----
// one wave/node, 2 feats/lane. Indices batched 64/coalesced-load, broadcast via readlane,
// gathers unrolled x4 for MLP.
template<bool FINAL>
__global__ __launch_bounds__(256) void k_agg(
    const unsigned short* __restrict__ t, const int* __restrict__ ssrc,
    const int* __restrict__ row_ptr, const int* __restrict__ deg,
    const float* __restrict__ dinv, const float* __restrict__ bias,
    void* __restrict__ out_v)
{
    const int wave = threadIdx.x >> 6;
    const int lane = threadIdx.x & 63;
    const int node = blockIdx.x * 4 + wave;
    if (node >= N_NODES) return;

    const int beg = row_ptr[node];
    const int cnt = deg[node] - 1;
    float a0 = 0.0f, a1 = 0.0f;

    for (int kb = 0; kb < cnt; kb += 64) {
        const int rem = cnt - kb;
        const int lim = rem < 64 ? rem : 64;
        int sk = 0;
        if (lane < lim) sk = ssrc[beg + kb + lane];
        float wk = dinv[sk];

        int k = 0;
        for (; k + 4 <= lim; k += 4) {
            int s0 = __builtin_amdgcn_readlane(sk, k);
            int s1 = __builtin_amdgcn_readlane(sk, k + 1);
            int s2 = __builtin_amdgcn_readlane(sk, k + 2);
            int s3 = __builtin_amdgcn_readlane(sk, k + 3);
            unsigned int p0 = *(const unsigned int*)&t[(size_t)s0 * 128 + lane * 2];
            unsigned int p1 = *(const unsigned int*)&t[(size_t)s1 * 128 + lane * 2];
            unsigned int p2 = *(const unsigned int*)&t[(size_t)s2 * 128 + lane * 2];
            unsigned int p3 = *(const unsigned int*)&t[(size_t)s3 * 128 + lane * 2];
            float w0 = rdlanef(wk, k);
            float w1 = rdlanef(wk, k + 1);
            float w2 = rdlanef(wk, k + 2);
            float w3 = rdlanef(wk, k + 3);
            a0 = fmaf(w0, b2f((unsigned short)(p0 & 0xffffu)), a0);
            a1 = fmaf(w0, b2f((unsigned short)(p0 >> 16)), a1);
            a0 = fmaf(w1, b2f((unsigned short)(p1 & 0xffffu)), a0);
            a1 = fmaf(w1, b2f((unsigned short)(p1 >> 16)), a1);
            a0 = fmaf(w2, b2f((unsigned short)(p2 & 0xffffu)), a0);
            a1 = fmaf(w2, b2f((unsigned short)(p2 >> 16)), a1);
            a0 = fmaf(w3, b2f((unsigned short)(p3 & 0xffffu)), a0);
            a1 = fmaf(w3, b2f((unsigned short)(p3 >> 16)), a1);
        }
        for (; k < lim; ++k) {
            int s0 = __builtin_amdgcn_readlane(sk, k);
            float w0 = rdlanef(wk, k);
            unsigned int p0 = *(const unsigned int*)&t[(size_t)s0 * 128 + lane * 2];
            a0 = fmaf(w0, b2f((unsigned short)(p0 & 0xffffu)), a0);
            a1 = fmaf(w0, b2f((unsigned short)(p0 >> 16)), a1);
        }
    }

    float di = dinv[node];
    unsigned int ps = *(const unsigned int*)&t[(size_t)node * 128 + lane * 2];
    float s0 = b2f((unsigned short)(ps & 0xffffu));
    float s1 = b2f((unsigned short)(ps >> 16));
    f32x2 bv = *(const f32x2*)&bias[lane * 2];
    float o0 = fmaxf(di * a0 + di * di * s0 + bv[0], 0.0f);
    float o1 = fmaxf(di * a1 + di * di * s1 + bv[1], 0.0f);
    if (FINAL) {
        f32x2 po; po[0] = o0; po[1] = o1;
        *(f32x2*)((float*)out_v + (size_t)node * 128 + lane * 2) = po;
    } else {
        unsigned short* out = (unsigned short*)out_v;
        unsigned int po = (unsigned int)f2b(o0) | ((unsigned int)f2b(o1) << 16);
        *(unsigned int*)&out[(size_t)node * 128 + lane * 2] = po;
    }
}

// ---------------- launch ----------------
extern "C" void kernel_launch(void* const* d_in, const int* in_sizes, int n_in,
                              void* d_out, int out_size, void* d_ws, size_t ws_size,
                              hipStream_t stream)
{
    const float* x  = (const float*)d_in[0];
    const int*   ei = (const int*)d_in[1];
    const float* pW = (const float*)d_in[2];
    const float* pb = (const float*)d_in[3];
    const float* W1 = (const float*)d_in[4];
    const float* b1 = (const float*)d_in[5];
    const float* W2 = (const float*)d_in[6];
    const float* b2 = (const float*)d_in[7];
    const float* W3 = (const float*)d_in[8];
    const float* b3 = (const float*)d_in[9];
    const int* src = ei;
    const int* dst = ei + N_EDGES;

    char* ws = (char*)d_ws;
    size_t off = 0;
    auto alloc = [&](size_t bytes) -> char* {
        char* p = ws + off; off += (bytes + 255) & ~(size_t)255; return p;
    };
    const size_t NB = (size_t)N_NODES * 128;
    unsigned short* xb = (unsigned short*)alloc(NB * 2);
    unsigned short* xp = (unsigned short*)alloc(NB * 2);
    unsigned short* h1 = (unsigned short*)alloc(NB * 2);
    unsigned short* h2 = (unsigned short*)alloc(NB * 2);
    unsigned short* tb = (unsigned short*)alloc(NB * 2);
    unsigned short* Wb = (unsigned short*)alloc((size_t)114688 * 2);   // W^T bf16
    int*   deg  = (int*)alloc((size_t)N_NODES * 4);
    int*   rp   = (int*)alloc((size_t)N_NODES * 4);
    int*   cur  = (int*)alloc((size_t)N_NODES * 4);
    float* dinv = (float*)alloc((size_t)N_NODES * 4);
    int*   psum = (int*)alloc((size_t)SCAN_BLOCKS * 4);
    int*   poff = (int*)alloc((size_t)SCAN_BLOCKS * 4);
    int*   ssrc = (int*)alloc((size_t)(N_EDGES + N_NODES) * 4);

    unsigned short* pWt = Wb;
    unsigned short* W1t = Wb + 16384;
    unsigned short* W2t = Wb + 32768;
    unsigned short* W3t = Wb + 65536;

    // casts
    k_cast4<<<(int)(NB / 4 + 255) / 256, 256, 0, stream>>>(x, xb, (int)(NB / 4));
    k_castWT<<<(114688 + 255) / 256, 256, 0, stream>>>(pW, W1, W2, W3, Wb);

    // graph build
    k_init_deg<<<(N_NODES + 255) / 256, 256, 0, stream>>>(deg);
    k_hist<<<(N_EDGES + 255) / 256, 256, 0, stream>>>(dst, deg);
    k_deg_part<<<SCAN_BLOCKS, 256, 0, stream>>>(deg, psum);
    k_scan_off<<<1, 64, 0, stream>>>(psum, poff);
    k_scan_final<<<SCAN_BLOCKS, 256, 0, stream>>>(deg, poff, rp, cur, dinv);
    k_scatter<<<(N_EDGES + 255) / 256, 256, 0, stream>>>(src, dst, cur, ssrc);

    const int gblocks = (N_NODES + 127) / 128;
    const int ablocks = (N_NODES + 3) / 4;

    k_gemm<1, true, true><<<gblocks, 256, 0, stream>>>(xb, nullptr, nullptr, pWt, pb, xp);
    k_gemm<1, false, false><<<gblocks, 256, 0, stream>>>(xb, nullptr, nullptr, W1t, nullptr, tb);
    k_agg<false><<<ablocks, 256, 0, stream>>>(tb, ssrc, rp, deg, dinv, b1, h1);
    k_gemm<2, false, false><<<gblocks, 256, 0, stream>>>(xp, h1, nullptr, W2t, nullptr, tb);
    k_agg<false><<<ablocks, 256, 0, stream>>>(tb, ssrc, rp, deg, dinv, b2, h2);
    k_gemm<3, false, false><<<gblocks, 256, 0, stream>>>(xp, h1, h2, W3t, nullptr, tb);
    k_agg<true><<<ablocks, 256, 0, stream>>>(tb, ssrc, rp, deg, dinv, b3, d_out);
}

// Round 6
// 640.163 us; speedup vs baseline: 1.8434x; 1.0701x over previous
//
#include <hip/hip_runtime.h>

#define N_NODES 100000
#define N_EDGES 1600000

typedef __attribute__((ext_vector_type(8))) short bf16x8;
typedef __attribute__((ext_vector_type(4))) float f32x4;
typedef __attribute__((ext_vector_type(2))) float f32x2;
typedef __attribute__((ext_vector_type(4))) unsigned short u16x4;

__device__ __forceinline__ float b2f(unsigned short u) {
    union { unsigned int i; float f; } v; v.i = ((unsigned int)u) << 16; return v.f;
}
__device__ __forceinline__ unsigned short f2b(float f) {
    union { float ff; unsigned int i; } v; v.ff = f;
    unsigned int x = v.i;
    x += 0x7fffu + ((x >> 16) & 1u);   // round-to-nearest-even
    return (unsigned short)(x >> 16);
}
__device__ __forceinline__ float rdlanef(float v, int l) {
    return __uint_as_float(__builtin_amdgcn_readlane(__float_as_uint(v), l));
}

// ---------------- f32 -> bf16 cast of x ----------------
__global__ __launch_bounds__(256) void k_cast4(const float* __restrict__ in,
                                               unsigned short* __restrict__ out, int n4) {
    int i = blockIdx.x * 256 + threadIdx.x;
    if (i < n4) {
        f32x4 v = *(const f32x4*)&in[(size_t)i * 4];
        u16x4 o;
        o[0] = f2b(v[0]); o[1] = f2b(v[1]); o[2] = f2b(v[2]); o[3] = f2b(v[3]);
        *(u16x4*)&out[(size_t)i * 4] = o;
    }
}

// cast + TRANSPOSE all 4 weight matrices -> Wt[col][k] bf16, contiguous pW|W1|W2|W3
__global__ __launch_bounds__(256) void k_castWT(
    const float* __restrict__ pW, const float* __restrict__ W1,
    const float* __restrict__ W2, const float* __restrict__ W3,
    unsigned short* __restrict__ out)
{
    int i = blockIdx.x * 256 + threadIdx.x;   // flat output index, 114688 total
    if (i >= 114688) return;
    const float* src; int K, base;
    if (i < 16384)      { src = pW; K = 128; base = 0; }
    else if (i < 32768) { src = W1; K = 128; base = 16384; }
    else if (i < 65536) { src = W2; K = 256; base = 32768; }
    else                { src = W3; K = 384; base = 65536; }
    int loc = i - base;
    int col = loc / K, k = loc - col * K;
    out[i] = f2b(src[(size_t)k * 128 + col]);
}

// ---------------- graph build ----------------
__global__ void k_init_deg(int* deg) {
    int i = blockIdx.x * 256 + threadIdx.x;
    if (i < N_NODES) deg[i] = 1;   // self-loop
}

__global__ void k_hist(const int* __restrict__ dst, int* __restrict__ deg) {
    int e = blockIdx.x * 256 + threadIdx.x;
    if (e < N_EDGES) atomicAdd(&deg[dst[e]], 1);
}

#define SCAN_CHUNK 2048
#define SCAN_BLOCKS ((N_NODES + SCAN_CHUNK - 1) / SCAN_CHUNK)   // 49

__global__ __launch_bounds__(256) void k_deg_part(const int* __restrict__ deg,
                                                  int* __restrict__ psum) {
    int b = blockIdx.x, t = threadIdx.x;
    int base = b * SCAN_CHUNK + t * 8;
    int s = 0;
#pragma unroll
    for (int i = 0; i < 8; ++i) { int idx = base + i; if (idx < N_NODES) s += deg[idx]; }
    for (int o = 1; o < 64; o <<= 1) s += __shfl_xor(s, o, 64);
    __shared__ int ws[4];
    if ((t & 63) == 0) ws[t >> 6] = s;
    __syncthreads();
    if (t == 0) psum[b] = ws[0] + ws[1] + ws[2] + ws[3];
}

__global__ void k_scan_off(const int* __restrict__ psum, int* __restrict__ poff) {
    int t = threadIdx.x;          // 64 threads
    int v = (t < SCAN_BLOCKS) ? psum[t] : 0;
    int sc = v;
    for (int o = 1; o < 64; o <<= 1) { int u = __shfl_up(sc, o, 64); if (t >= o) sc += u; }
    if (t < SCAN_BLOCKS) poff[t] = sc - v;
}

__global__ __launch_bounds__(256) void k_scan_final(
    const int* __restrict__ deg, const int* __restrict__ poff,
    int* __restrict__ row_ptr, int* __restrict__ cursor, float* __restrict__ dinv)
{
    int b = blockIdx.x, t = threadIdx.x;
    int base = b * SCAN_CHUNK + t * 8;
    int v[8]; int s = 0;
#pragma unroll
    for (int i = 0; i < 8; ++i) { int idx = base + i; v[i] = (idx < N_NODES) ? deg[idx] : 0; s += v[i]; }
    int lane = t & 63, wv = t >> 6;
    int sc = s;
    for (int o = 1; o < 64; o <<= 1) { int u = __shfl_up(sc, o, 64); if (lane >= o) sc += u; }
    __shared__ int wsum[4];
    if (lane == 63) wsum[wv] = sc;
    __syncthreads();
    int woff = 0;
    for (int i = 0; i < wv; ++i) woff += wsum[i];
    int excl = poff[b] + woff + sc - s;
#pragma unroll
    for (int i = 0; i < 8; ++i) {
        int idx = base + i;
        if (idx < N_NODES) {
            row_ptr[idx] = excl; cursor[idx] = excl;
            dinv[idx] = rsqrtf((float)v[i]);
            excl += v[i];
        }
    }
}

// XCD-partitioned windowed scatter: blocks with (blockIdx&7)==w handle dst-window w.
// All writes to a given cache line come from one XCD-group -> merge in its L2.
#define SCAT_GROUPS 8
#define SCAT_WIN ((N_NODES + SCAT_GROUPS - 1) / SCAT_GROUPS)    // 12500
#define SCAT_BLOCKS 2048                                        // 256 blocks per group

__global__ __launch_bounds__(256) void k_scatter(
    const int* __restrict__ src, const int* __restrict__ dst,
    int* __restrict__ cursor, int* __restrict__ ssrc)
{
    const int w  = blockIdx.x & (SCAT_GROUPS - 1);
    const int g  = blockIdx.x >> 3;                 // block index within group, 0..255
    const int lo = w * SCAT_WIN;
    const int hi = (lo + SCAT_WIN < N_NODES) ? lo + SCAT_WIN : N_NODES;
    const int stride = (SCAT_BLOCKS / SCAT_GROUPS) * 256;   // 65536
    for (int e = g * 256 + threadIdx.x; e < N_EDGES; e += stride) {
        int d = dst[e];
        if (d >= lo && d < hi) {
            int p = atomicAdd(&cursor[d], 1);
            ssrc[p] = src[e];
        }
    }
}

// ---------------- GEMM: out[n,128] = relu?( concat(A0..A_{NC-1}) @ W + bias? ) ----------------
// B-fragments read directly from global W^T (L2-resident). No LDS, no barriers.
template<int NC, bool RELU, bool BIAS>
__global__ __launch_bounds__(256) void k_gemm(
    const unsigned short* __restrict__ A0, const unsigned short* __restrict__ A1,
    const unsigned short* __restrict__ A2, const unsigned short* __restrict__ WtG,
    const float* __restrict__ bias, unsigned short* __restrict__ out)
{
    const int tid  = threadIdx.x;
    const int wave = tid >> 6, lane = tid & 63;
    const int l15 = lane & 15, lg = lane >> 4;
    const int K = NC * 128;
    const int rbase = blockIdx.x * 128 + wave * 32;

    f32x4 acc[2][8];
#pragma unroll
    for (int i = 0; i < 2; ++i)
#pragma unroll
        for (int j = 0; j < 8; ++j) acc[i][j] = (f32x4)(0.0f);

    int ar0 = rbase + l15;      if (ar0 >= N_NODES) ar0 = N_NODES - 1;
    int ar1 = rbase + 16 + l15; if (ar1 >= N_NODES) ar1 = N_NODES - 1;

    for (int c = 0; c < NC; ++c) {
        const unsigned short* Ac = (c == 0) ? A0 : ((c == 1) ? A1 : A2);
#pragma unroll
        for (int ks = 0; ks < 4; ++ks) {
            const int ko = ks * 32 + lg * 8;
            bf16x8 a0 = *(const bf16x8*)&Ac[(size_t)ar0 * 128 + ko];
            bf16x8 a1 = *(const bf16x8*)&Ac[(size_t)ar1 * 128 + ko];
#pragma unroll
            for (int cf = 0; cf < 8; ++cf) {
                bf16x8 b = *(const bf16x8*)&WtG[(size_t)(cf * 16 + l15) * K + c * 128 + ko];
                acc[0][cf] = __builtin_amdgcn_mfma_f32_16x16x32_bf16(a0, b, acc[0][cf], 0, 0, 0);
                acc[1][cf] = __builtin_amdgcn_mfma_f32_16x16x32_bf16(a1, b, acc[1][cf], 0, 0, 0);
            }
        }
    }
#pragma unroll
    for (int ai = 0; ai < 2; ++ai) {
#pragma unroll
        for (int cf = 0; cf < 8; ++cf) {
            int col = cf * 16 + l15;
            float bv = BIAS ? bias[col] : 0.0f;
#pragma unroll
            for (int j = 0; j < 4; ++j) {
                int row = rbase + ai * 16 + lg * 4 + j;
                if (row < N_NODES) {
                    float v = acc[ai][cf][j] + bv;
                    if (RELU) v = fmaxf(v, 0.0f);
                    out[(size_t)row * 128 + col] = f2b(v);
                }
            }
        }
    }
}

// ---------------- aggregation: out = relu(dinv_i * sum(dinv_s * t_s) + dinv_i^2 * t_i + b) ----
// one wave/node, 2 feats/lane; 64 indices per coalesced batch, readlane broadcast, x8 MLP.
template<bool FINAL>
__global__ __launch_bounds__(256) void k_agg(
    const unsigned short* __restrict__ t, const int* __restrict__ ssrc,
    const int* __restrict__ row_ptr, const int* __restrict__ deg,
    const float* __restrict__ dinv, const float* __restrict__ bias,
    void* __restrict__ out_v)
{
    const int wave = threadIdx.x >> 6;
    const int lane = threadIdx.x & 63;
    const int node = blockIdx.x * 4 + wave;
    if (node >= N_NODES) return;

    const int beg = row_ptr[node];
    const int cnt = deg[node] - 1;
    float a0 = 0.0f, a1 = 0.0f;

    for (int kb = 0; kb < cnt; kb += 64) {
        const int rem = cnt - kb;
        const int lim = rem < 64 ? rem : 64;
        int sk = 0;
        if (lane < lim) sk = ssrc[beg + kb + lane];
        float wk = dinv[sk];

        int k = 0;
        for (; k + 8 <= lim; k += 8) {
            unsigned int p[8];
            float w[8];
#pragma unroll
            for (int u = 0; u < 8; ++u) {
                int s = __builtin_amdgcn_readlane(sk, k + u);
                p[u] = *(const unsigned int*)&t[(size_t)s * 128 + lane * 2];
                w[u] = rdlanef(wk, k + u);
            }
#pragma unroll
            for (int u = 0; u < 8; ++u) {
                a0 = fmaf(w[u], b2f((unsigned short)(p[u] & 0xffffu)), a0);
                a1 = fmaf(w[u], b2f((unsigned short)(p[u] >> 16)), a1);
            }
        }
        for (; k < lim; ++k) {
            int s0 = __builtin_amdgcn_readlane(sk, k);
            float w0 = rdlanef(wk, k);
            unsigned int p0 = *(const unsigned int*)&t[(size_t)s0 * 128 + lane * 2];
            a0 = fmaf(w0, b2f((unsigned short)(p0 & 0xffffu)), a0);
            a1 = fmaf(w0, b2f((unsigned short)(p0 >> 16)), a1);
        }
    }

    float di = dinv[node];
    unsigned int ps = *(const unsigned int*)&t[(size_t)node * 128 + lane * 2];
    float s0 = b2f((unsigned short)(ps & 0xffffu));
    float s1 = b2f((unsigned short)(ps >> 16));
    f32x2 bv = *(const f32x2*)&bias[lane * 2];
    float o0 = fmaxf(di * a0 + di * di * s0 + bv[0], 0.0f);
    float o1 = fmaxf(di * a1 + di * di * s1 + bv[1], 0.0f);
    if (FINAL) {
        f32x2 po; po[0] = o0; po[1] = o1;
        *(f32x2*)((float*)out_v + (size_t)node * 128 + lane * 2) = po;
    } else {
        unsigned short* out = (unsigned short*)out_v;
        unsigned int po = (unsigned int)f2b(o0) | ((unsigned int)f2b(o1) << 16);
        *(unsigned int*)&out[(size_t)node * 128 + lane * 2] = po;
    }
}

// ---------------- launch ----------------
extern "C" void kernel_launch(void* const* d_in, const int* in_sizes, int n_in,
                              void* d_out, int out_size, void* d_ws, size_t ws_size,
                              hipStream_t stream)
{
    const float* x  = (const float*)d_in[0];
    const int*   ei = (const int*)d_in[1];
    const float* pW = (const float*)d_in[2];
    const float* pb = (const float*)d_in[3];
    const float* W1 = (const float*)d_in[4];
    const float* b1 = (const float*)d_in[5];
    const float* W2 = (const float*)d_in[6];
    const float* b2 = (const float*)d_in[7];
    const float* W3 = (const float*)d_in[8];
    const float* b3 = (const float*)d_in[9];
    const int* src = ei;
    const int* dst = ei + N_EDGES;

    char* ws = (char*)d_ws;
    size_t off = 0;
    auto alloc = [&](size_t bytes) -> char* {
        char* p = ws + off; off += (bytes + 255) & ~(size_t)255; return p;
    };
    const size_t NB = (size_t)N_NODES * 128;
    unsigned short* xb = (unsigned short*)alloc(NB * 2);
    unsigned short* xp = (unsigned short*)alloc(NB * 2);
    unsigned short* h1 = (unsigned short*)alloc(NB * 2);
    unsigned short* h2 = (unsigned short*)alloc(NB * 2);
    unsigned short* tb = (unsigned short*)alloc(NB * 2);
    unsigned short* Wb = (unsigned short*)alloc((size_t)114688 * 2);   // W^T bf16
    int*   deg  = (int*)alloc((size_t)N_NODES * 4);
    int*   rp   = (int*)alloc((size_t)N_NODES * 4);
    int*   cur  = (int*)alloc((size_t)N_NODES * 4);
    float* dinv = (float*)alloc((size_t)N_NODES * 4);
    int*   psum = (int*)alloc((size_t)SCAN_BLOCKS * 4);
    int*   poff = (int*)alloc((size_t)SCAN_BLOCKS * 4);
    int*   ssrc = (int*)alloc((size_t)(N_EDGES + N_NODES) * 4);

    unsigned short* pWt = Wb;
    unsigned short* W1t = Wb + 16384;
    unsigned short* W2t = Wb + 32768;
    unsigned short* W3t = Wb + 65536;

    // casts
    k_cast4<<<(int)(NB / 4 + 255) / 256, 256, 0, stream>>>(x, xb, (int)(NB / 4));
    k_castWT<<<(114688 + 255) / 256, 256, 0, stream>>>(pW, W1, W2, W3, Wb);

    // graph build
    k_init_deg<<<(N_NODES + 255) / 256, 256, 0, stream>>>(deg);
    k_hist<<<(N_EDGES + 255) / 256, 256, 0, stream>>>(dst, deg);
    k_deg_part<<<SCAN_BLOCKS, 256, 0, stream>>>(deg, psum);
    k_scan_off<<<1, 64, 0, stream>>>(psum, poff);
    k_scan_final<<<SCAN_BLOCKS, 256, 0, stream>>>(deg, poff, rp, cur, dinv);
    k_scatter<<<SCAT_BLOCKS, 256, 0, stream>>>(src, dst, cur, ssrc);

    const int gblocks = (N_NODES + 127) / 128;
    const int ablocks = (N_NODES + 3) / 4;

    k_gemm<1, true, true><<<gblocks, 256, 0, stream>>>(xb, nullptr, nullptr, pWt, pb, xp);
    k_gemm<1, false, false><<<gblocks, 256, 0, stream>>>(xb, nullptr, nullptr, W1t, nullptr, tb);
    k_agg<false><<<ablocks, 256, 0, stream>>>(tb, ssrc, rp, deg, dinv, b1, h1);
    k_gemm<2, false, false><<<gblocks, 256, 0, stream>>>(xp, h1, nullptr, W2t, nullptr, tb);
    k_agg<false><<<ablocks, 256, 0, stream>>>(tb, ssrc, rp, deg, dinv, b2, h2);
    k_gemm<3, false, false><<<gblocks, 256, 0, stream>>>(xp, h1, h2, W3t, nullptr, tb);
    k_agg<true><<<ablocks, 256, 0, stream>>>(tb, ssrc, rp, deg, dinv, b3, d_out);
}